// Round 2
// baseline (515.874 us; speedup 1.0000x reference)
//
#include <hip/hip_runtime.h>

#define DM 1024
#define NH 16
#define DH 64
#define BB 4
#define SS 2048
#define MROWS (BB*SS)

typedef __bf16 bf16;
typedef __bf16 bf16x8 __attribute__((ext_vector_type(8)));
typedef __bf16 bf16x4 __attribute__((ext_vector_type(4)));
typedef float floatx4 __attribute__((ext_vector_type(4)));

// ---------------------------------------------------------------------------
// x: fp32 -> bf16, 8 elems/thread, exact grid
// ---------------------------------------------------------------------------
__global__ __launch_bounds__(256) void cvt_x(
    const float* __restrict__ X, bf16* __restrict__ Y) {
  int i = (blockIdx.x * 256 + threadIdx.x) * 8;
  float4 a = *(const float4*)&X[i];
  float4 b = *(const float4*)&X[i + 4];
  bf16x8 o;
  o[0] = (bf16)a.x; o[1] = (bf16)a.y; o[2] = (bf16)a.z; o[3] = (bf16)a.w;
  o[4] = (bf16)b.x; o[5] = (bf16)b.y; o[6] = (bf16)b.z; o[7] = (bf16)b.w;
  *(bf16x8*)&Y[i] = o;
}

// ---------------------------------------------------------------------------
// Weight convert+transpose: T[n][k] = (bf16)W[k][n], fp32 1024x1024 input,
// 4 weights via blockIdx.z
// ---------------------------------------------------------------------------
__global__ __launch_bounds__(1024) void wtransc(
    const float* __restrict__ W0, const float* __restrict__ W1,
    const float* __restrict__ W2, const float* __restrict__ W3,
    bf16* __restrict__ T0, bf16* __restrict__ T1,
    bf16* __restrict__ T2, bf16* __restrict__ T3) {
  __shared__ float tile[32][33];
  const float* W; bf16* T;
  int z = blockIdx.z;
  if (z == 0)      { W = W0; T = T0; }
  else if (z == 1) { W = W1; T = T1; }
  else if (z == 2) { W = W2; T = T2; }
  else             { W = W3; T = T3; }
  int tx = threadIdx.x, ty = threadIdx.y;
  tile[ty][tx] = W[(blockIdx.y * 32 + ty) * DM + blockIdx.x * 32 + tx];
  __syncthreads();
  T[(blockIdx.x * 32 + ty) * DM + blockIdx.y * 32 + tx] = (bf16)tile[tx][ty];
}

// ---------------------------------------------------------------------------
// GEMM: C[M,N] = A[M,K] @ WT[N,K]^T + bias.  M=8192, N=K=1024.  A/WT bf16,
// bias fp32, fp32 accumulate, OutT output.  Block tile 128x64, 4 waves (2x2)
// of 64x32, BK=32.  MFMA 16x16x32 bf16 verified layouts:
//   A frag: A[m=lane&15][k=quad*8+j]   B frag: B[k=quad*8+j][n=lane&15]
//   C/D   : col=lane&15, row=quad*4+reg
// ---------------------------------------------------------------------------
#define BM 128
#define BN 64
#define BK 32
#define LDS_S 40  // BK + 8 pad, keeps 16B alignment, breaks pow2 bank stride

template <typename OutT>
__global__ __launch_bounds__(256) void gemm_bias(
    const bf16* __restrict__ A, const bf16* __restrict__ WT,
    const float* __restrict__ bias, OutT* __restrict__ C) {
  __shared__ __align__(16) bf16 As[BM][LDS_S];
  __shared__ __align__(16) bf16 Bs[BN][LDS_S];
  int tid = threadIdx.x;
  int lane = tid & 63, wid = tid >> 6;
  int wm = (wid >> 1) * 64;
  int wn = (wid & 1) * 32;
  int m0 = blockIdx.y * BM;
  int n0 = blockIdx.x * BN;
  int qd = lane >> 4;
  int l15 = lane & 15;

  floatx4 acc[4][2] = {};

  for (int k0 = 0; k0 < DM; k0 += BK) {
    __syncthreads();
    for (int i = 0; i < 2; ++i) {
      int c = tid + i * 256;
      int r = c >> 2, cc = (c & 3) * 8;
      *(bf16x8*)&As[r][cc] = *(const bf16x8*)&A[(m0 + r) * DM + k0 + cc];
    }
    {
      int r = tid >> 2, cc = (tid & 3) * 8;
      *(bf16x8*)&Bs[r][cc] = *(const bf16x8*)&WT[(n0 + r) * DM + k0 + cc];
    }
    __syncthreads();
    bf16x8 af[4], bfr[2];
    for (int mt = 0; mt < 4; ++mt)
      af[mt] = *(const bf16x8*)&As[wm + mt * 16 + l15][qd * 8];
    for (int nt = 0; nt < 2; ++nt)
      bfr[nt] = *(const bf16x8*)&Bs[wn + nt * 16 + l15][qd * 8];
    for (int mt = 0; mt < 4; ++mt)
      for (int nt = 0; nt < 2; ++nt)
        acc[mt][nt] = __builtin_amdgcn_mfma_f32_16x16x32_bf16(
            af[mt], bfr[nt], acc[mt][nt], 0, 0, 0);
  }

  for (int nt = 0; nt < 2; ++nt) {
    int col = n0 + wn + nt * 16 + l15;
    float bv = bias[col];
    for (int mt = 0; mt < 4; ++mt)
      for (int r = 0; r < 4; ++r) {
        int row = m0 + wm + mt * 16 + qd * 4 + r;
        C[row * DM + col] = (OutT)(acc[mt][nt][r] + bv);
      }
  }
}

// ---------------------------------------------------------------------------
// Flash attention, causal.  One block = 64 q-rows of one (b,h); 4 waves each
// owning 16 q-rows.  K-tiles of 64 keys.  Q pre-scaled by 0.125 (exact).
// Online softmax fp32; P round-trips per-wave LDS (C-layout -> A-layout).
// ---------------------------------------------------------------------------
#define LK 72
#define LV 68
#define LP 72

__global__ __launch_bounds__(256) void attn_fwd(
    const bf16* __restrict__ Q, const bf16* __restrict__ K,
    const bf16* __restrict__ V, bf16* __restrict__ O) {
  __shared__ __align__(16) bf16 Ks[64][LK];
  __shared__ __align__(16) bf16 Vt[64][LV];
  __shared__ __align__(16) bf16 Ps[4][16][LP];

  int tid = threadIdx.x;
  int lane = tid & 63, w = tid >> 6;
  int qd = lane >> 4, l15 = lane & 15;
  int qt = blockIdx.x, h = blockIdx.y, b = blockIdx.z;
  int q0 = qt * 64;
  int base = b * SS;
  int hoff = h * DH;

  bf16x8 qf[2];
  {
    int qrow = base + q0 + w * 16 + l15;
    for (int ks = 0; ks < 2; ++ks) {
      bf16x8 t = *(const bf16x8*)&Q[qrow * DM + hoff + ks * 32 + qd * 8];
      for (int j = 0; j < 8; ++j) t[j] = (bf16)((float)t[j] * 0.125f);
      qf[ks] = t;
    }
  }

  float m_r[4], l_r[4];
  floatx4 oacc[4] = {};
  for (int r = 0; r < 4; ++r) { m_r[r] = -1e30f; l_r[r] = 0.0f; }

  for (int kt = 0; kt <= qt; ++kt) {
    __syncthreads();
    for (int i = 0; i < 2; ++i) {
      int c = tid + i * 256;
      int key = c >> 3, dc = (c & 7) * 8;
      int grow = base + kt * 64 + key;
      *(bf16x8*)&Ks[key][dc] = *(const bf16x8*)&K[grow * DM + hoff + dc];
      bf16x8 t = *(const bf16x8*)&V[grow * DM + hoff + dc];
      for (int j = 0; j < 8; ++j) Vt[dc + j][key] = t[j];
    }
    __syncthreads();

    floatx4 s[4] = {};
    for (int nt = 0; nt < 4; ++nt)
      for (int ks = 0; ks < 2; ++ks) {
        bf16x8 kf = *(const bf16x8*)&Ks[nt * 16 + l15][ks * 32 + qd * 8];
        s[nt] = __builtin_amdgcn_mfma_f32_16x16x32_bf16(qf[ks], kf, s[nt], 0, 0, 0);
      }

    if (kt == qt) {
      for (int nt = 0; nt < 4; ++nt) {
        int col = kt * 64 + nt * 16 + l15;
        for (int r = 0; r < 4; ++r) {
          int row = q0 + w * 16 + qd * 4 + r;
          if (col > row) s[nt][r] = -1e30f;
        }
      }
    }

    float alpha[4];
    for (int r = 0; r < 4; ++r) {
      float t = fmaxf(fmaxf(s[0][r], s[1][r]), fmaxf(s[2][r], s[3][r]));
      for (int d = 1; d < 16; d <<= 1) t = fmaxf(t, __shfl_xor(t, d, 64));
      float mn = fmaxf(m_r[r], t);
      alpha[r] = __expf(m_r[r] - mn);
      m_r[r] = mn;
    }
    float psum[4] = {0.f, 0.f, 0.f, 0.f};
    for (int nt = 0; nt < 4; ++nt)
      for (int r = 0; r < 4; ++r) {
        float p = __expf(s[nt][r] - m_r[r]);
        s[nt][r] = p;
        psum[r] += p;
      }
    for (int r = 0; r < 4; ++r) {
      float t = psum[r];
      for (int d = 1; d < 16; d <<= 1) t += __shfl_xor(t, d, 64);
      l_r[r] = l_r[r] * alpha[r] + t;
    }
    for (int dt = 0; dt < 4; ++dt)
      for (int r = 0; r < 4; ++r) oacc[dt][r] *= alpha[r];

    for (int nt = 0; nt < 4; ++nt)
      for (int r = 0; r < 4; ++r)
        Ps[w][qd * 4 + r][nt * 16 + l15] = (bf16)s[nt][r];
    __syncthreads();

    bf16x8 pf[2];
    for (int ks = 0; ks < 2; ++ks)
      pf[ks] = *(const bf16x8*)&Ps[w][l15][ks * 32 + qd * 8];

    for (int dt = 0; dt < 4; ++dt)
      for (int ks = 0; ks < 2; ++ks) {
        const bf16* vp = &Vt[dt * 16 + l15][ks * 32 + qd * 8];
        bf16x4 v0 = *(const bf16x4*)vp;
        bf16x4 v1 = *(const bf16x4*)(vp + 4);
        bf16x8 vf = {v0[0], v0[1], v0[2], v0[3], v1[0], v1[1], v1[2], v1[3]};
        oacc[dt] = __builtin_amdgcn_mfma_f32_16x16x32_bf16(pf[ks], vf, oacc[dt], 0, 0, 0);
      }
  }

  for (int r = 0; r < 4; ++r) {
    float inv = 1.0f / l_r[r];
    int row = base + q0 + w * 16 + qd * 4 + r;
    for (int dt = 0; dt < 4; ++dt) {
      int dcol = dt * 16 + l15;
      O[row * DM + hoff + dcol] = (bf16)(oacc[dt][r] * inv);
    }
  }
}

// ---------------------------------------------------------------------------
extern "C" void kernel_launch(void* const* d_in, const int* in_sizes, int n_in,
                              void* d_out, int out_size, void* d_ws, size_t ws_size,
                              hipStream_t stream) {
  const float* x  = (const float*)d_in[0];
  const float* Wq = (const float*)d_in[1];
  const float* bq = (const float*)d_in[2];
  const float* Wk = (const float*)d_in[3];
  const float* bk = (const float*)d_in[4];
  const float* Wv = (const float*)d_in[5];
  const float* bv = (const float*)d_in[6];
  const float* Wo = (const float*)d_in[7];
  const float* bo = (const float*)d_in[8];
  float* out = (float*)d_out;

  char* ws = (char*)d_ws;
  const size_t act = (size_t)MROWS * DM * sizeof(bf16);  // 16.8 MB
  bf16* xb  = (bf16*)(ws);
  bf16* qb  = (bf16*)(ws + act);
  bf16* kb  = (bf16*)(ws + 2 * act);
  bf16* vb  = (bf16*)(ws + 3 * act);
  bf16* ab  = (bf16*)(ws + 4 * act);
  bf16* WqT = (bf16*)(ws + 5 * act);
  bf16* WkT = WqT + (size_t)DM * DM;
  bf16* WvT = WkT + (size_t)DM * DM;
  bf16* WoT = WvT + (size_t)DM * DM;

  cvt_x<<<MROWS * DM / (256 * 8), 256, 0, stream>>>(x, xb);
  wtransc<<<dim3(32, 32, 4), dim3(32, 32), 0, stream>>>(
      Wq, Wk, Wv, Wo, WqT, WkT, WvT, WoT);

  dim3 gg(DM / BN, MROWS / BM);  // (16, 64)
  gemm_bias<bf16><<<gg, 256, 0, stream>>>(xb, WqT, bq, qb);
  gemm_bias<bf16><<<gg, 256, 0, stream>>>(xb, WkT, bk, kb);
  gemm_bias<bf16><<<gg, 256, 0, stream>>>(xb, WvT, bv, vb);

  attn_fwd<<<dim3(SS / 64, NH, BB), 256, 0, stream>>>(qb, kb, vb, ab);

  gemm_bias<float><<<gg, 256, 0, stream>>>(ab, WoT, bo, out);
}

// Round 3
// 373.317 us; speedup vs baseline: 1.3819x; 1.3819x over previous
//
#include <hip/hip_runtime.h>
#include <math.h>

#define DM 1024
#define NH 16
#define DH 64
#define BB 4
#define SS 2048
#define MROWS (BB*SS)

typedef __bf16 bf16;
typedef __bf16 bf16x8 __attribute__((ext_vector_type(8)));
typedef __bf16 bf16x4 __attribute__((ext_vector_type(4)));
typedef float floatx4 __attribute__((ext_vector_type(4)));

// ---------------------------------------------------------------------------
// x: fp32 -> bf16, 8 elems/thread
// ---------------------------------------------------------------------------
__global__ __launch_bounds__(256) void cvt_x(
    const float* __restrict__ X, bf16* __restrict__ Y) {
  int i = (blockIdx.x * 256 + threadIdx.x) * 8;
  float4 a = *(const float4*)&X[i];
  float4 b = *(const float4*)&X[i + 4];
  bf16x8 o;
  o[0] = (bf16)a.x; o[1] = (bf16)a.y; o[2] = (bf16)a.z; o[3] = (bf16)a.w;
  o[4] = (bf16)b.x; o[5] = (bf16)b.y; o[6] = (bf16)b.z; o[7] = (bf16)b.w;
  *(bf16x8*)&Y[i] = o;
}

// ---------------------------------------------------------------------------
// Weight convert+transpose: T[n][k] = (bf16)W[k][n]
// ---------------------------------------------------------------------------
__global__ __launch_bounds__(1024) void wtransc(
    const float* __restrict__ W0, const float* __restrict__ W1,
    const float* __restrict__ W2, const float* __restrict__ W3,
    bf16* __restrict__ T0, bf16* __restrict__ T1,
    bf16* __restrict__ T2, bf16* __restrict__ T3) {
  __shared__ float tile[32][33];
  const float* W; bf16* T;
  int z = blockIdx.z;
  if (z == 0)      { W = W0; T = T0; }
  else if (z == 1) { W = W1; T = T1; }
  else if (z == 2) { W = W2; T = T2; }
  else             { W = W3; T = T3; }
  int tx = threadIdx.x, ty = threadIdx.y;
  tile[ty][tx] = W[(blockIdx.y * 32 + ty) * DM + blockIdx.x * 32 + tx];
  __syncthreads();
  T[(blockIdx.x * 32 + ty) * DM + blockIdx.y * 32 + tx] = (bf16)tile[tx][ty];
}

// ---------------------------------------------------------------------------
// GEMM: C[M,N] = A[M,K] @ WT[N,K]^T + bias.  128x128 block tile, 4 waves
// (2x2) of 64x64, BK=32, register prefetch of next k-step.
// MFMA 16x16x32 bf16 verified layouts:
//   A frag: A[m=lane&15][k=quad*8+j]   B frag: B[k=quad*8+j][n=lane&15]
//   C/D   : col=lane&15, row=quad*4+reg
// ---------------------------------------------------------------------------
#define BM 128
#define BN 128
#define BK 32
#define LDS_S 40  // BK + 8 pad; 16B-aligned rows

template <typename OutT>
__global__ __launch_bounds__(256) void gemm_bias(
    const bf16* __restrict__ A, const bf16* __restrict__ WT,
    const float* __restrict__ bias, OutT* __restrict__ C) {
  __shared__ __align__(16) bf16 As[BM][LDS_S];
  __shared__ __align__(16) bf16 Bs[BN][LDS_S];
  int tid = threadIdx.x;
  int lane = tid & 63, wid = tid >> 6;
  int wm = (wid >> 1) * 64;
  int wn = (wid & 1) * 64;
  int m0 = blockIdx.y * BM;
  int n0 = blockIdx.x * BN;
  int qd = lane >> 4;
  int l15 = lane & 15;

  // staging coords: 512 chunks of 8 per matrix tile, 2 per thread
  int sr[2], sc[2];
  for (int i = 0; i < 2; ++i) {
    int c = tid + i * 256;
    sr[i] = c >> 2; sc[i] = (c & 3) * 8;
  }

  floatx4 acc[4][4] = {};
  bf16x8 areg[2], breg[2];
  for (int i = 0; i < 2; ++i) {
    areg[i] = *(const bf16x8*)&A[(m0 + sr[i]) * DM + sc[i]];
    breg[i] = *(const bf16x8*)&WT[(n0 + sr[i]) * DM + sc[i]];
  }

  for (int k0 = 0; k0 < DM; k0 += BK) {
    __syncthreads();
    for (int i = 0; i < 2; ++i) {
      *(bf16x8*)&As[sr[i]][sc[i]] = areg[i];
      *(bf16x8*)&Bs[sr[i]][sc[i]] = breg[i];
    }
    __syncthreads();
    int kn = (k0 + BK < DM) ? k0 + BK : k0;  // clamp: last iter reloads
    for (int i = 0; i < 2; ++i) {
      areg[i] = *(const bf16x8*)&A[(m0 + sr[i]) * DM + kn + sc[i]];
      breg[i] = *(const bf16x8*)&WT[(n0 + sr[i]) * DM + kn + sc[i]];
    }
    bf16x8 af[4], bfr[4];
    for (int mt = 0; mt < 4; ++mt)
      af[mt] = *(const bf16x8*)&As[wm + mt * 16 + l15][qd * 8];
    for (int nt = 0; nt < 4; ++nt)
      bfr[nt] = *(const bf16x8*)&Bs[wn + nt * 16 + l15][qd * 8];
    for (int mt = 0; mt < 4; ++mt)
      for (int nt = 0; nt < 4; ++nt)
        acc[mt][nt] = __builtin_amdgcn_mfma_f32_16x16x32_bf16(
            af[mt], bfr[nt], acc[mt][nt], 0, 0, 0);
  }

  for (int nt = 0; nt < 4; ++nt) {
    int col = n0 + wn + nt * 16 + l15;
    float bv = bias[col];
    for (int mt = 0; mt < 4; ++mt)
      for (int r = 0; r < 4; ++r) {
        int row = m0 + wm + mt * 16 + qd * 4 + r;
        C[row * DM + col] = (OutT)(acc[mt][nt][r] + bv);
      }
  }
}

// ---------------------------------------------------------------------------
// Flash attention, causal.  One block handles TWO 128-row q-tiles (qt and
// 15-qt -> uniform 34 k-tiles per block; grid 512 = 2 blocks/CU, zero tail).
// 4 waves, each owns 32 q-rows (2 mt-groups of 16).  K-tile 64 keys.
// Register prefetch of next K/V tile overlaps global latency with compute.
// Ps is per-wave private: NO barrier for the P layout round-trip.
// Q pre-scaled by 0.125*log2e; softmax runs in exp2 domain.
// ---------------------------------------------------------------------------
#define LK 72
#define LV 68
#define LP 72

__global__ __launch_bounds__(256) void attn_fwd(
    const bf16* __restrict__ Q, const bf16* __restrict__ K,
    const bf16* __restrict__ V, bf16* __restrict__ O) {
  __shared__ __align__(16) bf16 Ks[64][LK];
  __shared__ __align__(16) bf16 Vt[64][LV];
  __shared__ __align__(16) bf16 Ps[4][32][LP];

  int tid = threadIdx.x;
  int lane = tid & 63, w = tid >> 6;
  int qd = lane >> 4, l15 = lane & 15;
  int pair = blockIdx.x, h = blockIdx.y, b = blockIdx.z;
  int base = b * SS;
  int hoff = h * DH;

  // staging coords: 64 keys x 64 d = 512 chunks, 2 per thread
  int skey[2], sdc[2];
  for (int i = 0; i < 2; ++i) {
    int c = tid + i * 256;
    skey[i] = c >> 3; sdc[i] = (c & 7) * 8;
  }

  const float qs = 0.125f * 1.44269504088896f;  // Dh^-0.5 * log2(e)

  for (int ph = 0; ph < 2; ++ph) {
    int qt = ph ? (15 - pair) : pair;
    int q0 = qt * 128;
    int nkt = 2 * qt + 2;

    bf16x8 qf[2][2];
    for (int mt = 0; mt < 2; ++mt) {
      int qrow = base + q0 + w * 32 + mt * 16 + l15;
      for (int ks = 0; ks < 2; ++ks) {
        bf16x8 t = *(const bf16x8*)&Q[qrow * DM + hoff + ks * 32 + qd * 8];
        for (int j = 0; j < 8; ++j) t[j] = (bf16)((float)t[j] * qs);
        qf[mt][ks] = t;
      }
    }

    float m_r[2][4], l_r[2][4];
    floatx4 oacc[2][4] = {};
    for (int mt = 0; mt < 2; ++mt)
      for (int r = 0; r < 4; ++r) { m_r[mt][r] = -3e38f; l_r[mt][r] = 0.0f; }

    // prefetch tile 0
    bf16x8 kreg[2], vreg[2];
    for (int i = 0; i < 2; ++i) {
      int grow = base + skey[i];
      kreg[i] = *(const bf16x8*)&K[grow * DM + hoff + sdc[i]];
      vreg[i] = *(const bf16x8*)&V[grow * DM + hoff + sdc[i]];
    }

    for (int kt = 0; kt < nkt; ++kt) {
      __syncthreads();  // previous tile's readers done
      for (int i = 0; i < 2; ++i) {
        *(bf16x8*)&Ks[skey[i]][sdc[i]] = kreg[i];
        for (int j = 0; j < 8; ++j) Vt[sdc[i] + j][skey[i]] = vreg[i][j];
      }
      __syncthreads();
      // prefetch next tile while computing this one
      int nk = (kt + 1 < nkt) ? kt + 1 : kt;
      for (int i = 0; i < 2; ++i) {
        int grow = base + nk * 64 + skey[i];
        kreg[i] = *(const bf16x8*)&K[grow * DM + hoff + sdc[i]];
        vreg[i] = *(const bf16x8*)&V[grow * DM + hoff + sdc[i]];
      }

      // S = Q K^T
      floatx4 s[2][4] = {};
      for (int nt = 0; nt < 4; ++nt)
        for (int ks = 0; ks < 2; ++ks) {
          bf16x8 kf = *(const bf16x8*)&Ks[nt * 16 + l15][ks * 32 + qd * 8];
          for (int mt = 0; mt < 2; ++mt)
            s[mt][nt] = __builtin_amdgcn_mfma_f32_16x16x32_bf16(
                qf[mt][ks], kf, s[mt][nt], 0, 0, 0);
        }

      // causal mask (only the two diagonal-crossing tiles need it)
      if (kt >= 2 * qt) {
        for (int mt = 0; mt < 2; ++mt)
          for (int nt = 0; nt < 4; ++nt) {
            int col = kt * 64 + nt * 16 + l15;
            for (int r = 0; r < 4; ++r) {
              int row = q0 + w * 32 + mt * 16 + qd * 4 + r;
              if (col > row) s[mt][nt][r] = -3e38f;
            }
          }
      }

      // online softmax in exp2 domain
      float alpha[2][4];
      for (int mt = 0; mt < 2; ++mt)
        for (int r = 0; r < 4; ++r) {
          float t = fmaxf(fmaxf(s[mt][0][r], s[mt][1][r]),
                          fmaxf(s[mt][2][r], s[mt][3][r]));
          for (int d = 1; d < 16; d <<= 1) t = fmaxf(t, __shfl_xor(t, d, 64));
          float mn = fmaxf(m_r[mt][r], t);
          alpha[mt][r] = exp2f(m_r[mt][r] - mn);
          m_r[mt][r] = mn;
        }
      float psum[2][4] = {};
      for (int mt = 0; mt < 2; ++mt)
        for (int nt = 0; nt < 4; ++nt)
          for (int r = 0; r < 4; ++r) {
            float p = exp2f(s[mt][nt][r] - m_r[mt][r]);
            s[mt][nt][r] = p;
            psum[mt][r] += p;
          }
      for (int mt = 0; mt < 2; ++mt)
        for (int r = 0; r < 4; ++r) {
          float t = psum[mt][r];
          for (int d = 1; d < 16; d <<= 1) t += __shfl_xor(t, d, 64);
          l_r[mt][r] = l_r[mt][r] * alpha[mt][r] + t;
        }
      for (int mt = 0; mt < 2; ++mt)
        for (int dt = 0; dt < 4; ++dt)
          for (int r = 0; r < 4; ++r) oacc[mt][dt][r] *= alpha[mt][r];

      // P: C-layout -> per-wave LDS -> A-layout (no barrier: wave-private)
      for (int mt = 0; mt < 2; ++mt)
        for (int nt = 0; nt < 4; ++nt)
          for (int r = 0; r < 4; ++r)
            Ps[w][mt * 16 + qd * 4 + r][nt * 16 + l15] = (bf16)s[mt][nt][r];

      bf16x8 pf[2][2];
      for (int mt = 0; mt < 2; ++mt)
        for (int ks = 0; ks < 2; ++ks)
          pf[mt][ks] = *(const bf16x8*)&Ps[w][mt * 16 + l15][ks * 32 + qd * 8];

      // O += P V
      for (int dt = 0; dt < 4; ++dt)
        for (int ks = 0; ks < 2; ++ks) {
          const bf16* vp = &Vt[dt * 16 + l15][ks * 32 + qd * 8];
          bf16x4 v0 = *(const bf16x4*)vp;
          bf16x4 v1 = *(const bf16x4*)(vp + 4);
          bf16x8 vf = {v0[0], v0[1], v0[2], v0[3], v1[0], v1[1], v1[2], v1[3]};
          for (int mt = 0; mt < 2; ++mt)
            oacc[mt][dt] = __builtin_amdgcn_mfma_f32_16x16x32_bf16(
                pf[mt][ks], vf, oacc[mt][dt], 0, 0, 0);
        }
    }

    for (int mt = 0; mt < 2; ++mt)
      for (int r = 0; r < 4; ++r) {
        float inv = 1.0f / l_r[mt][r];
        int row = base + q0 + w * 32 + mt * 16 + qd * 4 + r;
        for (int dt = 0; dt < 4; ++dt)
          O[row * DM + hoff + dt * 16 + l15] = (bf16)(oacc[mt][dt][r] * inv);
      }
  }
}

// ---------------------------------------------------------------------------
extern "C" void kernel_launch(void* const* d_in, const int* in_sizes, int n_in,
                              void* d_out, int out_size, void* d_ws, size_t ws_size,
                              hipStream_t stream) {
  const float* x  = (const float*)d_in[0];
  const float* Wq = (const float*)d_in[1];
  const float* bq = (const float*)d_in[2];
  const float* Wk = (const float*)d_in[3];
  const float* bk = (const float*)d_in[4];
  const float* Wv = (const float*)d_in[5];
  const float* bv = (const float*)d_in[6];
  const float* Wo = (const float*)d_in[7];
  const float* bo = (const float*)d_in[8];
  float* out = (float*)d_out;

  char* ws = (char*)d_ws;
  const size_t act = (size_t)MROWS * DM * sizeof(bf16);  // 16.8 MB
  bf16* xb  = (bf16*)(ws);
  bf16* qb  = (bf16*)(ws + act);
  bf16* kb  = (bf16*)(ws + 2 * act);
  bf16* vb  = (bf16*)(ws + 3 * act);
  bf16* ab  = (bf16*)(ws + 4 * act);
  bf16* WqT = (bf16*)(ws + 5 * act);
  bf16* WkT = WqT + (size_t)DM * DM;
  bf16* WvT = WkT + (size_t)DM * DM;
  bf16* WoT = WvT + (size_t)DM * DM;

  cvt_x<<<MROWS * DM / (256 * 8), 256, 0, stream>>>(x, xb);
  wtransc<<<dim3(32, 32, 4), dim3(32, 32), 0, stream>>>(
      Wq, Wk, Wv, Wo, WqT, WkT, WvT, WoT);

  dim3 gg(DM / BN, MROWS / BM);  // (8, 64)
  gemm_bias<bf16><<<gg, 256, 0, stream>>>(xb, WqT, bq, qb);
  gemm_bias<bf16><<<gg, 256, 0, stream>>>(xb, WkT, bk, kb);
  gemm_bias<bf16><<<gg, 256, 0, stream>>>(xb, WvT, bv, vb);

  attn_fwd<<<dim3(8, NH, BB), 256, 0, stream>>>(qb, kb, vb, ab);

  gemm_bias<float><<<gg, 256, 0, stream>>>(ab, WoT, bo, out);
}

// Round 4
// 315.910 us; speedup vs baseline: 1.6330x; 1.1817x over previous
//
#include <hip/hip_runtime.h>
#include <math.h>

#define DM 1024
#define NH 16
#define DH 64
#define BB 4
#define SS 2048
#define MROWS (BB*SS)

typedef __bf16 bf16;
typedef __bf16 bf16x8 __attribute__((ext_vector_type(8)));
typedef float floatx4 __attribute__((ext_vector_type(4)));

#if __has_builtin(__builtin_amdgcn_exp2f)
#define EXP2F __builtin_amdgcn_exp2f
#else
#define EXP2F exp2f
#endif

// async 16B global->LDS; lds dest = wave-uniform base + lane*16 (HW rule)
__device__ __forceinline__ void cp16(void* lds, const void* g) {
  __builtin_amdgcn_global_load_lds(
      (__attribute__((address_space(1))) void*)(void*)g,
      (__attribute__((address_space(3))) void*)lds,
      16, 0, 0);
}

// ---------------------------------------------------------------------------
// x: fp32 -> bf16
// ---------------------------------------------------------------------------
__global__ __launch_bounds__(256) void cvt_x(
    const float* __restrict__ X, bf16* __restrict__ Y) {
  int i = (blockIdx.x * 256 + threadIdx.x) * 8;
  float4 a = *(const float4*)&X[i];
  float4 b = *(const float4*)&X[i + 4];
  bf16x8 o;
  o[0] = (bf16)a.x; o[1] = (bf16)a.y; o[2] = (bf16)a.z; o[3] = (bf16)a.w;
  o[4] = (bf16)b.x; o[5] = (bf16)b.y; o[6] = (bf16)b.z; o[7] = (bf16)b.w;
  *(bf16x8*)&Y[i] = o;
}

// ---------------------------------------------------------------------------
// Weight convert+transpose: T[n][k] = (bf16)W[k][n]
// ---------------------------------------------------------------------------
__global__ __launch_bounds__(1024) void wtransc(
    const float* __restrict__ W0, const float* __restrict__ W1,
    const float* __restrict__ W2, const float* __restrict__ W3,
    bf16* __restrict__ T0, bf16* __restrict__ T1,
    bf16* __restrict__ T2, bf16* __restrict__ T3) {
  __shared__ float tile[32][33];
  const float* W; bf16* T;
  int z = blockIdx.z;
  if (z == 0)      { W = W0; T = T0; }
  else if (z == 1) { W = W1; T = T1; }
  else if (z == 2) { W = W2; T = T2; }
  else             { W = W3; T = T3; }
  int tx = threadIdx.x, ty = threadIdx.y;
  tile[ty][tx] = W[(blockIdx.y * 32 + ty) * DM + blockIdx.x * 32 + tx];
  __syncthreads();
  T[(blockIdx.x * 32 + ty) * DM + blockIdx.y * 32 + tx] = (bf16)tile[tx][ty];
}

// ---------------------------------------------------------------------------
// V transpose: T[1024][8192] = S[8192][1024]^T  (bf16)
// ---------------------------------------------------------------------------
__global__ __launch_bounds__(1024) void vtrans(
    const bf16* __restrict__ S, bf16* __restrict__ T) {
  __shared__ bf16 tile[32][33];
  int tx = threadIdx.x, ty = threadIdx.y;
  tile[ty][tx] = S[(size_t)(blockIdx.y * 32 + ty) * DM + blockIdx.x * 32 + tx];
  __syncthreads();
  T[(size_t)(blockIdx.x * 32 + ty) * MROWS + blockIdx.y * 32 + tx] = tile[tx][ty];
}

// ---------------------------------------------------------------------------
// GEMM: C[M,N] = A[M,K] @ WT[N,K]^T + bias.  128x128 tile, 4 waves 64x64,
// BK=32.  global_load_lds(16B) staging, single-barrier LDS double-buffer:
// per k-step: issue async loads(t+1 -> buf^1), compute buf, barrier (the
// implicit vmcnt(0)-before-s_barrier drains loads AFTER compute = overlap).
// Unpadded [128][32] tiles: frag-read banks are exactly balanced (8 dw/bank).
// ---------------------------------------------------------------------------
#define BM 128
#define BN 128
#define BK 32

template <typename OutT>
__global__ __launch_bounds__(256, 2) void gemm_bias(
    const bf16* __restrict__ A, const bf16* __restrict__ WT,
    const float* __restrict__ bias, OutT* __restrict__ C) {
  __shared__ __align__(16) bf16 As[2][BM * BK];
  __shared__ __align__(16) bf16 Bs[2][BM * BK];
  int tid = threadIdx.x;
  int lane = tid & 63, w = tid >> 6;
  int wm = (w >> 1) * 64;
  int wn = (w & 1) * 64;
  int m0 = blockIdx.y * BM;
  int n0 = blockIdx.x * BN;
  int qd = lane >> 4;
  int l15 = lane & 15;

  floatx4 acc[4][4] = {};

  auto stage = [&](int pb, int k0) {
    for (int i = 0; i < 2; ++i) {
      int ci = (w * 2 + i) * 64;       // chunk base (wave-uniform)
      int c = ci + lane;
      int r = c >> 2, cc = (c & 3) * 8;
      cp16(&As[pb][ci * 8], &A[(size_t)(m0 + r) * DM + k0 + cc]);
      cp16(&Bs[pb][ci * 8], &WT[(size_t)(n0 + r) * DM + k0 + cc]);
    }
  };

  stage(0, 0);
  __syncthreads();

  for (int t = 0; t < DM / BK; ++t) {
    int pb = t & 1;
    if (t + 1 < DM / BK) stage(pb ^ 1, (t + 1) * BK);
    bf16x8 af[4], bfr[4];
    for (int mt = 0; mt < 4; ++mt)
      af[mt] = *(const bf16x8*)&As[pb][(wm + mt * 16 + l15) * BK + qd * 8];
    for (int nt = 0; nt < 4; ++nt)
      bfr[nt] = *(const bf16x8*)&Bs[pb][(wn + nt * 16 + l15) * BK + qd * 8];
    for (int mt = 0; mt < 4; ++mt)
      for (int nt = 0; nt < 4; ++nt)
        acc[mt][nt] = __builtin_amdgcn_mfma_f32_16x16x32_bf16(
            af[mt], bfr[nt], acc[mt][nt], 0, 0, 0);
    __syncthreads();
  }

  for (int nt = 0; nt < 4; ++nt) {
    int col = n0 + wn + nt * 16 + l15;
    float bv = bias[col];
    for (int mt = 0; mt < 4; ++mt)
      for (int r = 0; r < 4; ++r) {
        int row = m0 + wm + mt * 16 + qd * 4 + r;
        C[(size_t)row * DM + col] = (OutT)(acc[mt][nt][r] + bv);
      }
  }
}

// ---------------------------------------------------------------------------
// Flash attention, causal.  Block = two 128-row q-tiles (qt, 15-qt): uniform
// 34 k-tiles/block, grid 512 = 2/CU.  4 waves x 32 q-rows.  K-tile 64 keys.
// K/V staged by global_load_lds into XOR-swizzled unpadded [row][64] tiles
// (chunk' = chunk ^ (row&7) -> balanced banks), single-barrier double-buffer.
// V comes from globally pre-transposed vt[d][s].  Softmax: shared max per
// 16-row group (valid guard; 8 shuffles/tile), l-sum via MFMA with B=ones
// (C-layout, row-consistent with oacc).  Ps is wave-private (no barrier).
// ---------------------------------------------------------------------------
__global__ __launch_bounds__(256, 2) void attn_fwd(
    const bf16* __restrict__ Qg, const bf16* __restrict__ Kg,
    const bf16* __restrict__ Vt, bf16* __restrict__ O) {
  __shared__ __align__(16) bf16 Kbuf[2][64 * 64];
  __shared__ __align__(16) bf16 Vbuf[2][64 * 64];
  __shared__ __align__(16) bf16 Ps[4][32][72];

  int tid = threadIdx.x;
  int lane = tid & 63, w = tid >> 6;
  int qd = lane >> 4, l15 = lane & 15;
  int sw = l15 & 7;                       // frag-read xor swizzle
  int pair = blockIdx.x, h = blockIdx.y, b = blockIdx.z;
  int base = b * SS;
  int hoff = h * DH;

  // staging: 512 chunks/tile; wave w, instr i covers chunks (w*2+i)*64+lane.
  // row = chunk>>3; phys col-chunk = lane&7; logical = (lane&7)^(row&7).
  int gch = ((lane & 7) ^ (lane >> 3)) * 8;   // logical col element offset
  auto stage = [&](int pb, int kt) {
    int kbase = base + kt * 64;
    for (int i = 0; i < 2; ++i) {
      int ci = (w * 2 + i) * 64;
      int row = (ci + lane) >> 3;           // key (K) / d (V)
      cp16(&Kbuf[pb][ci * 8], &Kg[(size_t)(kbase + row) * DM + hoff + gch]);
      cp16(&Vbuf[pb][ci * 8],
           &Vt[(size_t)(hoff + row) * MROWS + base + kt * 64 + gch]);
    }
  };

  bf16x8 onesf;
  for (int j = 0; j < 8; ++j) onesf[j] = (bf16)1.0f;
  const float qs = 0.125f * 1.44269504088896f;  // Dh^-0.5 * log2(e)

  for (int ph = 0; ph < 2; ++ph) {
    int qt = ph ? (15 - pair) : pair;
    int q0 = qt * 128;
    int nkt = 2 * qt + 2;

    stage(0, 0);  // async; previous phase's last barrier guarantees safety

    bf16x8 qf[2][2];
    for (int mt = 0; mt < 2; ++mt) {
      int qrow = base + q0 + w * 32 + mt * 16 + l15;
      for (int ks = 0; ks < 2; ++ks) {
        bf16x8 t = *(const bf16x8*)&Qg[(size_t)qrow * DM + hoff + ks * 32 + qd * 8];
        for (int j = 0; j < 8; ++j) t[j] = (bf16)((float)t[j] * qs);
        qf[mt][ks] = t;
      }
    }

    float m_r[2] = {-3e38f, -3e38f};
    floatx4 lacc[2] = {};
    floatx4 oacc[2][4] = {};

    __syncthreads();  // drains tile-0 loads (vmcnt(0) before s_barrier)

    for (int kt = 0; kt < nkt; ++kt) {
      int pb = kt & 1;
      if (kt + 1 < nkt) stage(pb ^ 1, kt + 1);  // async across compute

      // S = Q K^T
      floatx4 s[2][4] = {};
      for (int ks = 0; ks < 2; ++ks)
        for (int nt = 0; nt < 4; ++nt) {
          bf16x8 kf = *(const bf16x8*)
              &Kbuf[pb][(nt * 16 + l15) * 64 + (((ks << 2) + qd) ^ sw) * 8];
          s[0][nt] = __builtin_amdgcn_mfma_f32_16x16x32_bf16(
              qf[0][ks], kf, s[0][nt], 0, 0, 0);
          s[1][nt] = __builtin_amdgcn_mfma_f32_16x16x32_bf16(
              qf[1][ks], kf, s[1][nt], 0, 0, 0);
        }

      if (kt >= 2 * qt) {  // diagonal tiles: causal mask
        for (int mt = 0; mt < 2; ++mt)
          for (int nt = 0; nt < 4; ++nt) {
            int col = kt * 64 + nt * 16 + l15;
            for (int r = 0; r < 4; ++r) {
              int row = q0 + w * 32 + mt * 16 + qd * 4 + r;
              if (col > row) s[mt][nt][r] = -3e38f;
            }
          }
      }

      // online softmax: shared max per 16-row group (mt)
      for (int mt = 0; mt < 2; ++mt) {
        float t = s[mt][0][0];
        for (int nt = 0; nt < 4; ++nt)
          for (int r = 0; r < 4; ++r) t = fmaxf(t, s[mt][nt][r]);
        t = fmaxf(t, __shfl_xor(t, 1, 64));
        t = fmaxf(t, __shfl_xor(t, 2, 64));
        t = fmaxf(t, __shfl_xor(t, 4, 64));
        t = fmaxf(t, __shfl_xor(t, 8, 64));
        float mn = fmaxf(m_r[mt], t);
        float al = EXP2F(m_r[mt] - mn);
        m_r[mt] = mn;
        for (int dt = 0; dt < 4; ++dt)
          for (int r = 0; r < 4; ++r) oacc[mt][dt][r] *= al;
        for (int r = 0; r < 4; ++r) lacc[mt][r] *= al;
        for (int nt = 0; nt < 4; ++nt)
          for (int r = 0; r < 4; ++r) {
            float p = EXP2F(s[mt][nt][r] - mn);
            Ps[w][mt * 16 + qd * 4 + r][nt * 16 + l15] = (bf16)p;
          }
      }

      // P: wave-private LDS round trip, no barrier
      bf16x8 pf[2][2];
      for (int mt = 0; mt < 2; ++mt)
        for (int ks = 0; ks < 2; ++ks)
          pf[mt][ks] = *(const bf16x8*)&Ps[w][mt * 16 + l15][ks * 32 + qd * 8];

      // O += P V ; l += P @ ones
      for (int ks = 0; ks < 2; ++ks)
        for (int dt = 0; dt < 4; ++dt) {
          bf16x8 vf = *(const bf16x8*)
              &Vbuf[pb][(dt * 16 + l15) * 64 + (((ks << 2) + qd) ^ sw) * 8];
          oacc[0][dt] = __builtin_amdgcn_mfma_f32_16x16x32_bf16(
              pf[0][ks], vf, oacc[0][dt], 0, 0, 0);
          oacc[1][dt] = __builtin_amdgcn_mfma_f32_16x16x32_bf16(
              pf[1][ks], vf, oacc[1][dt], 0, 0, 0);
        }
      for (int mt = 0; mt < 2; ++mt)
        for (int ks = 0; ks < 2; ++ks)
          lacc[mt] = __builtin_amdgcn_mfma_f32_16x16x32_bf16(
              pf[mt][ks], onesf, lacc[mt], 0, 0, 0);

      __syncthreads();  // single barrier/tile: drains async loads post-compute
    }

    for (int mt = 0; mt < 2; ++mt)
      for (int r = 0; r < 4; ++r) {
        float inv = 1.0f / lacc[mt][r];
        int row = base + q0 + w * 32 + mt * 16 + qd * 4 + r;
        for (int dt = 0; dt < 4; ++dt)
          O[(size_t)row * DM + hoff + dt * 16 + l15] = (bf16)(oacc[mt][dt][r] * inv);
      }
  }
}

// ---------------------------------------------------------------------------
extern "C" void kernel_launch(void* const* d_in, const int* in_sizes, int n_in,
                              void* d_out, int out_size, void* d_ws, size_t ws_size,
                              hipStream_t stream) {
  const float* x  = (const float*)d_in[0];
  const float* Wq = (const float*)d_in[1];
  const float* bq = (const float*)d_in[2];
  const float* Wk = (const float*)d_in[3];
  const float* bk = (const float*)d_in[4];
  const float* Wv = (const float*)d_in[5];
  const float* bv = (const float*)d_in[6];
  const float* Wo = (const float*)d_in[7];
  const float* bo = (const float*)d_in[8];
  float* out = (float*)d_out;

  char* ws = (char*)d_ws;
  const size_t act = (size_t)MROWS * DM * sizeof(bf16);  // 16.8 MB
  bf16* xb  = (bf16*)(ws);
  bf16* qb  = (bf16*)(ws + act);
  bf16* kb  = (bf16*)(ws + 2 * act);
  bf16* vb  = (bf16*)(ws + 3 * act);
  bf16* vt  = (bf16*)(ws + 4 * act);
  bf16* WqT = (bf16*)(ws + 5 * act);
  bf16* WkT = WqT + (size_t)DM * DM;
  bf16* WvT = WkT + (size_t)DM * DM;
  bf16* WoT = WvT + (size_t)DM * DM;
  bf16* ab  = vb;  // vb dead after vtrans; attn writes its output here

  cvt_x<<<MROWS * DM / (256 * 8), 256, 0, stream>>>(x, xb);
  wtransc<<<dim3(32, 32, 4), dim3(32, 32), 0, stream>>>(
      Wq, Wk, Wv, Wo, WqT, WkT, WvT, WoT);

  dim3 gg(DM / BN, MROWS / BM);  // (8, 64)
  gemm_bias<bf16><<<gg, 256, 0, stream>>>(xb, WqT, bq, qb);
  gemm_bias<bf16><<<gg, 256, 0, stream>>>(xb, WkT, bk, kb);
  gemm_bias<bf16><<<gg, 256, 0, stream>>>(xb, WvT, bv, vb);

  vtrans<<<dim3(DM / 32, MROWS / 32), dim3(32, 32), 0, stream>>>(vb, vt);

  attn_fwd<<<dim3(8, NH, BB), 256, 0, stream>>>(qb, kb, vt, ab);

  gemm_bias<float><<<gg, 256, 0, stream>>>(ab, WoT, bo, out);
}